// Round 6
// baseline (1057.467 us; speedup 1.0000x reference)
//
#include <hip/hip_runtime.h>
#include <stdint.h>

#define MROWS 8192   // B*S
#define DDIM  2048
#define HDIM  8192

typedef __attribute__((ext_vector_type(8))) short bf16x8;
typedef __attribute__((ext_vector_type(4))) float f32x4;
typedef __attribute__((ext_vector_type(4))) int   i32x4;
typedef unsigned short u16;

__device__ __forceinline__ void async_load16(const void* g, void* l) {
  auto gp = reinterpret_cast<const __attribute__((address_space(1))) unsigned int*>(
      reinterpret_cast<uintptr_t>(g));
  auto lp = reinterpret_cast<__attribute__((address_space(3))) unsigned int*>(
      reinterpret_cast<uintptr_t>(l));
  __builtin_amdgcn_global_load_lds(gp, lp, 16, 0, 0);
}

__device__ __forceinline__ u16 f2bf(float f) {
  union { float f; unsigned int u; } v; v.f = f;
  unsigned int r = v.u + 0x7FFF + ((v.u >> 16) & 1);
  return (u16)(r >> 16);
}

// ---------------- sign(w) -> int8 {+1,-1,0}; blockIdx.y picks Wg/Wu ----------------
__global__ void sign_i8x2_kernel(const float* __restrict__ wg, const float* __restrict__ wu,
                                 char* __restrict__ og, char* __restrict__ ou) {
  const int t = blockIdx.x * 256 + threadIdx.x;
  const float* w = blockIdx.y ? wu : wg;
  char* o = blockIdx.y ? ou : og;
  const float4* w4 = (const float4*)w;
  float4 a = w4[t * 2], b = w4[t * 2 + 1];
  float v[8] = {a.x, a.y, a.z, a.w, b.x, b.y, b.z, b.w};
  union { char s[8]; uint2 u; } pk;
#pragma unroll
  for (int i = 0; i < 8; i++)
    pk.s[i] = v[i] > 0.f ? (char)1 : (v[i] < 0.f ? (char)-1 : (char)0);
  ((uint2*)o)[t] = pk.u;
}

// ---------------- sign(w) -> bf16 {+1,-1,0} (for W_d) ----------------
__global__ void sign_bf16_kernel(const float* __restrict__ w, u16* __restrict__ o) {
  const int t = blockIdx.x * 256 + threadIdx.x;
  const float4* w4 = (const float4*)w;
  float4 a = w4[t * 2], b = w4[t * 2 + 1];
  float v[8] = {a.x, a.y, a.z, a.w, b.x, b.y, b.z, b.w};
  union { u16 s[8]; uint4 u; } pk;
#pragma unroll
  for (int i = 0; i < 8; i++)
    pk.s[i] = v[i] > 0.f ? 0x3F80 : (v[i] < 0.f ? 0xBF80 : 0);
  ((uint4*)o)[t] = pk.u;
}

// ---------------- fused layernorm + activation_quant -> int8 q + row scale ----------------
__global__ void norm_quant_i8_kernel(const float* __restrict__ x,
                                     char* __restrict__ q, float* __restrict__ inv) {
  const int row  = blockIdx.x;
  const int tid  = threadIdx.x;
  const int lane = tid & 63, wave = tid >> 6;
  const float4* xr = (const float4*)(x + (size_t)row * DDIM);
  float4 a = xr[tid * 2], b = xr[tid * 2 + 1];
  float v[8] = {a.x, a.y, a.z, a.w, b.x, b.y, b.z, b.w};
  float s1 = 0.f, s2 = 0.f;
#pragma unroll
  for (int i = 0; i < 8; i++) { s1 += v[i]; s2 += v[i] * v[i]; }
#pragma unroll
  for (int o = 1; o < 64; o <<= 1) { s1 += __shfl_xor(s1, o); s2 += __shfl_xor(s2, o); }
  __shared__ float ssum[4], ssq[4], smax[4];
  if (lane == 0) { ssum[wave] = s1; ssq[wave] = s2; }
  __syncthreads();
  s1 = ssum[0] + ssum[1] + ssum[2] + ssum[3];
  s2 = ssq[0] + ssq[1] + ssq[2] + ssq[3];
  const float mean = s1 * (1.f / DDIM);
  const float var  = s2 * (1.f / DDIM) - mean * mean;
  const float rstd = rsqrtf(var + 1e-8f);
  float mx = 0.f;
#pragma unroll
  for (int i = 0; i < 8; i++) { v[i] = (v[i] - mean) * rstd; mx = fmaxf(mx, fabsf(v[i])); }
#pragma unroll
  for (int o = 1; o < 64; o <<= 1) mx = fmaxf(mx, __shfl_xor(mx, o));
  if (lane == 0) smax[wave] = mx;
  __syncthreads();
  mx = fmaxf(fmaxf(smax[0], smax[1]), fmaxf(smax[2], smax[3]));
  const float s = 127.f / mx;
  if (tid == 0) inv[row] = mx * (1.f / 127.f);
  union { char s8[8]; uint2 u; } pk;
#pragma unroll
  for (int i = 0; i < 8; i++) {
    float qq = rintf(v[i] * s);               // round half-to-even like jnp.round
    qq = fminf(fmaxf(qq, -128.f), 127.f);
    pk.s8[i] = (char)(int)qq;
  }
  ((uint2*)(q + (size_t)row * DDIM))[tid] = pk.u;
}

// ---------------- fused GEMM1+2 (int8): p = silu(g)*u, exact integer dot ----------------
// r0-proven structure: 128x128 tile, BK=128 bytes, XOR-swizzled LDS, XCD-rect block
// swizzle, 48KB LDS. launch_bounds(256,3): request 3 blocks/CU (144KB LDS, VGPR 108
// allows it) -> more m114 cross-block overlap. Only change vs the 266-277us anchor.
__global__ __launch_bounds__(256, 3) void gemm_glu_i8_kernel(
    const char* __restrict__ A,   // q [MROWS, DDIM] int8
    const char* __restrict__ Bg,  // sign(W_g) [HDIM, DDIM] int8
    const char* __restrict__ Bu,  // sign(W_u) [HDIM, DDIM] int8
    const float* __restrict__ inv,
    u16* __restrict__ P)          // [MROWS, HDIM] bf16
{
  constexpr int K = DDIM;         // bytes per row (int8)
  // XCD-aware swizzle: XCD x owns n-tiles [8x, 8x+8); consecutive slots share m-stripe.
  const int l   = blockIdx.x + gridDim.x * blockIdx.y;  // 0..4095
  const int xcd = l & 7;
  const int s_  = l >> 3;                               // 0..511
  const int n0 = (xcd * 8 + (s_ & 7)) * 128;
  const int m0 = (s_ >> 3) * 128;
  const int tid  = threadIdx.x;
  const int lane = tid & 63, wave = tid >> 6;
  const int wm = wave >> 1, wn = wave & 1;
  const int quad = lane >> 4, l16 = lane & 15;

  __shared__ __align__(16) char lds[49152];
  char* lA  = lds;
  char* lBg = lds + 16384;
  char* lBu = lds + 32768;

  i32x4 accg[4][4], accu[4][4];
  const i32x4 zero = {0, 0, 0, 0};
#pragma unroll
  for (int i = 0; i < 4; i++)
#pragma unroll
    for (int j = 0; j < 4; j++) { accg[i][j] = zero; accu[i][j] = zero; }

  const int arow = wm * 64 + l16;
  const int brow = wn * 64 + l16;
  const int aswz = (arow & 7) << 4;
  const int bswz = (brow & 7) << 4;

  for (int k0 = 0; k0 < K; k0 += 128) {
    __syncthreads();
#pragma unroll
    for (int is = 0; is < 4; ++is) {
      const int o   = is * 4096 + tid * 16;
      const int r   = o >> 7;                      // tile row 0..127
      const int cbs = (o & 127) ^ ((r & 7) << 4);  // swizzled byte-in-row
      async_load16(A  + (size_t)(m0 + r) * K + k0 + cbs, lA  + is * 4096 + wave * 1024);
      async_load16(Bg + (size_t)(n0 + r) * K + k0 + cbs, lBg + is * 4096 + wave * 1024);
      async_load16(Bu + (size_t)(n0 + r) * K + k0 + cbs, lBu + is * 4096 + wave * 1024);
    }
    __syncthreads();
#pragma unroll
    for (int ks = 0; ks < 2; ++ks) {
      const int koff = ks * 64 + quad * 16;
      i32x4 a[4], bg[4], bu[4];
#pragma unroll
      for (int i = 0; i < 4; i++)
        a[i] = *(const i32x4*)(lA + (arow + i * 16) * 128 + (koff ^ aswz));
#pragma unroll
      for (int j = 0; j < 4; j++) {
        bg[j] = *(const i32x4*)(lBg + (brow + j * 16) * 128 + (koff ^ bswz));
        bu[j] = *(const i32x4*)(lBu + (brow + j * 16) * 128 + (koff ^ bswz));
      }
#pragma unroll
      for (int i = 0; i < 4; i++)
#pragma unroll
        for (int j = 0; j < 4; j++) {
          accg[i][j] = __builtin_amdgcn_mfma_i32_16x16x64_i8(a[i], bg[j], accg[i][j], 0, 0, 0);
          accu[i][j] = __builtin_amdgcn_mfma_i32_16x16x64_i8(a[i], bu[j], accu[i][j], 0, 0, 0);
        }
    }
  }

  // epilogue: g,u exact ints scaled by row scale; p = silu(g)*u -> bf16
  const int rbase = m0 + wm * 64 + quad * 4;
  const int cbase = n0 + wn * 64 + l16;
#pragma unroll
  for (int i = 0; i < 4; i++) {
    float iv[4];
#pragma unroll
    for (int r = 0; r < 4; r++) iv[r] = inv[rbase + i * 16 + r];
#pragma unroll
    for (int j = 0; j < 4; j++)
#pragma unroll
      for (int r = 0; r < 4; r++) {
        float g = (float)accg[i][j][r] * iv[r];
        float u = (float)accu[i][j][r] * iv[r];
        float pv = (g / (1.f + __expf(-g))) * u;
        P[(size_t)(rbase + i * 16 + r) * HDIM + (cbase + j * 16)] = f2bf(pv);
      }
  }
}

// ---------------- GEMM3: out = p @ sign(W_d)^T, bf16 in / fp32 out ----------------
// m201 geometry: BM=BN=256, BK=128B (64 bf16), 8 waves (2Mx4N), 128x64/wave.
// Counted vmcnt (see tile-boundary comment). Rect-XCD swizzle: each XCD owns a
// 4n x 8m rectangle -> per-XCD L2 fill 48MB (4 B-panels + 8 P-stripes) vs 132MB
// for the 1n x 32m column mapping. Predicted FETCH_SIZE 540 -> ~350MB.
__global__ __launch_bounds__(512, 2) void gemm_out_kernel(
    const u16* __restrict__ A,  // p [MROWS, HDIM]
    const u16* __restrict__ B,  // sign(W_d) [DDIM, HDIM]
    float* __restrict__ C)      // [MROWS, DDIM]
{
  constexpr size_t KB = (size_t)HDIM * 2;  // 16384 bytes per row
  constexpr int NT = (int)(KB / 128);      // 128 K-tiles
  const int l   = blockIdx.x + gridDim.x * blockIdx.y;  // grid (8,32) -> 0..255
  const int xcd = l & 7;
  const int s_  = l >> 3;                               // 0..31
  const int n0 = ((xcd & 1) * 4 + (s_ & 3)) * 256;      // 8 n-positions
  const int m0 = ((xcd >> 1) * 8 + (s_ >> 2)) * 256;    // 32 m-positions
  const int tid  = threadIdx.x;
  const int lane = tid & 63, wave = tid >> 6;
  const int wm = wave >> 2, wn = wave & 3;
  const int quad = lane >> 4, l16 = lane & 15;

  __shared__ __align__(16) char lds[131072];

  f32x4 acc[8][4];
  const f32x4 zero = {0.f, 0.f, 0.f, 0.f};
#pragma unroll
  for (int i = 0; i < 8; i++)
#pragma unroll
    for (int j = 0; j < 4; j++) acc[i][j] = zero;

  const int arow = wm * 128 + l16;
  const int brow = wn * 64 + l16;
  const int swz  = (l16 & 7) << 4;

  const int rr  = tid >> 3;
  const int cbs = ((tid & 7) << 4) ^ ((rr & 7) << 4);
  const char* aSrc = (const char*)A + (size_t)(m0 + rr) * KB + cbs;
  const char* bSrc = (const char*)B + (size_t)(n0 + rr) * KB + cbs;

#define STG2_A(is) async_load16(aSrc + (size_t)(is) * 64 * KB + k0n, bufN + (is) * 8192 + wave * 1024)
#define STG2_B(is) async_load16(bSrc + (size_t)(is) * 64 * KB + k0n, bufN + 32768 + (is) * 8192 + wave * 1024)
#define STG2_TILE() do { STG2_A(0); STG2_A(1); STG2_A(2); STG2_A(3); \
                         STG2_B(0); STG2_B(1); STG2_B(2); STG2_B(3); } while (0)

  {
    char* bufN = lds;           const int k0n = 0;
    STG2_TILE();
  }
  {
    char* bufN = lds + 65536;   const int k0n = 128;
    STG2_TILE();
  }
  asm volatile("s_waitcnt vmcnt(8)" ::: "memory");
  __builtin_amdgcn_s_barrier();

  for (int t = 0; t < NT; ++t) {
    const char* bufC = lds + (size_t)(t & 1) * 65536;
    bf16x8 b[4];
#pragma unroll
    for (int ks = 0; ks < 2; ++ks) {
#pragma unroll
      for (int ih = 0; ih < 2; ++ih) {
        const int koff = (ks * 64 + quad * 16) ^ swz;
        if (ih == 0) {  // B frags once per ks, reused across ih phases
#pragma unroll
          for (int j = 0; j < 4; ++j)
            b[j] = *(const bf16x8*)(bufC + 32768 + (size_t)(brow + j * 16) * 128 + koff);
        }
        bf16x8 a[4];
#pragma unroll
        for (int ii = 0; ii < 4; ++ii)
          a[ii] = *(const bf16x8*)(bufC + (size_t)(arow + (ih * 4 + ii) * 16) * 128 + koff);
        __builtin_amdgcn_s_barrier();     // phase barrier
        __builtin_amdgcn_s_setprio(1);
#pragma unroll
        for (int ii = 0; ii < 4; ++ii) {
          const int i = ih * 4 + ii;
#pragma unroll
          for (int j = 0; j < 4; ++j)
            acc[i][j] = __builtin_amdgcn_mfma_f32_16x16x32_bf16(a[ii], b[j], acc[i][j], 0, 0, 0);
        }
        __builtin_amdgcn_s_setprio(0);
      }
    }
    __builtin_amdgcn_s_barrier();         // B1: all reads of bufC done
    if (t + 2 < NT) {
      char* bufN = lds + (size_t)(t & 1) * 65536;
      const int k0n = (t + 2) * 128;
      STG2_TILE();
      asm volatile("s_waitcnt vmcnt(8)" ::: "memory");
    } else {
      asm volatile("s_waitcnt vmcnt(0)" ::: "memory");
    }
    __builtin_amdgcn_s_barrier();
  }
#undef STG2_A
#undef STG2_B
#undef STG2_TILE

  const int rbase = m0 + wm * 128 + quad * 4;
  const int cbase = n0 + wn * 64 + l16;
#pragma unroll
  for (int i = 0; i < 8; i++)
#pragma unroll
    for (int j = 0; j < 4; j++)
#pragma unroll
      for (int r = 0; r < 4; r++)
        C[(size_t)(rbase + i * 16 + r) * DDIM + (cbase + j * 16)] = acc[i][j][r];
}

extern "C" void kernel_launch(void* const* d_in, const int* in_sizes, int n_in,
                              void* d_out, int out_size, void* d_ws, size_t ws_size,
                              hipStream_t stream) {
  const float* x  = (const float*)d_in[0];
  const float* Wg = (const float*)d_in[1];
  const float* Wu = (const float*)d_in[2];
  const float* Wd = (const float*)d_in[3];

  char* ws = (char*)d_ws;
  // layout: q(16MB) | inv(32KB @16MB) | sWg_i8(16MB @20MB) | sWu_i8(16MB @36MB)
  //         | sWd_bf16(32MB @52MB) | p(128MB @84MB)  -> 212MB total
  char*  q    = ws;
  float* inv  = (float*)(ws + 16777216ull);
  char*  sWg  = ws + 20971520ull;
  char*  sWu  = ws + 37748736ull;
  u16*   sWd  = (u16*)(ws + 54525952ull);
  u16*   p    = (u16*)(ws + 88080384ull);
  float* out  = (float*)d_out;

  dim3 gs(8192, 2);
  sign_i8x2_kernel<<<gs, 256, 0, stream>>>(Wg, Wu, sWg, sWu);
  sign_bf16_kernel<<<8192, 256, 0, stream>>>(Wd, sWd);

  norm_quant_i8_kernel<<<MROWS, 256, 0, stream>>>(x, q, inv);

  dim3 g1(HDIM / 128, MROWS / 128);   // 64 x 64 = 4096 blocks
  gemm_glu_i8_kernel<<<g1, 256, 0, stream>>>(q, sWg, sWu, inv, p);

  dim3 g2(DDIM / 256, MROWS / 256);   // 8 x 32 = 256 blocks
  gemm_out_kernel<<<g2, 512, 0, stream>>>(p, sWd, out);
}

// Round 7
// 707.140 us; speedup vs baseline: 1.4954x; 1.4954x over previous
//
#include <hip/hip_runtime.h>
#include <stdint.h>

#define MROWS 8192   // B*S
#define DDIM  2048
#define HDIM  8192

typedef __attribute__((ext_vector_type(8))) short bf16x8;
typedef __attribute__((ext_vector_type(4))) float f32x4;
typedef __attribute__((ext_vector_type(4))) int   i32x4;
typedef unsigned short u16;

__device__ __forceinline__ void async_load16(const void* g, void* l) {
  auto gp = reinterpret_cast<const __attribute__((address_space(1))) unsigned int*>(
      reinterpret_cast<uintptr_t>(g));
  auto lp = reinterpret_cast<__attribute__((address_space(3))) unsigned int*>(
      reinterpret_cast<uintptr_t>(l));
  __builtin_amdgcn_global_load_lds(gp, lp, 16, 0, 0);
}

__device__ __forceinline__ u16 f2bf(float f) {
  union { float f; unsigned int u; } v; v.f = f;
  unsigned int r = v.u + 0x7FFF + ((v.u >> 16) & 1);
  return (u16)(r >> 16);
}

// ---------------- sign(w) -> int8 {+1,-1,0}; blockIdx.y picks Wg/Wu ----------------
__global__ void sign_i8x2_kernel(const float* __restrict__ wg, const float* __restrict__ wu,
                                 char* __restrict__ og, char* __restrict__ ou) {
  const int t = blockIdx.x * 256 + threadIdx.x;
  const float* w = blockIdx.y ? wu : wg;
  char* o = blockIdx.y ? ou : og;
  const float4* w4 = (const float4*)w;
  float4 a = w4[t * 2], b = w4[t * 2 + 1];
  float v[8] = {a.x, a.y, a.z, a.w, b.x, b.y, b.z, b.w};
  union { char s[8]; uint2 u; } pk;
#pragma unroll
  for (int i = 0; i < 8; i++)
    pk.s[i] = v[i] > 0.f ? (char)1 : (v[i] < 0.f ? (char)-1 : (char)0);
  ((uint2*)o)[t] = pk.u;
}

// ---------------- sign(w) -> bf16 {+1,-1,0} (for W_d) ----------------
__global__ void sign_bf16_kernel(const float* __restrict__ w, u16* __restrict__ o) {
  const int t = blockIdx.x * 256 + threadIdx.x;
  const float4* w4 = (const float4*)w;
  float4 a = w4[t * 2], b = w4[t * 2 + 1];
  float v[8] = {a.x, a.y, a.z, a.w, b.x, b.y, b.z, b.w};
  union { u16 s[8]; uint4 u; } pk;
#pragma unroll
  for (int i = 0; i < 8; i++)
    pk.s[i] = v[i] > 0.f ? 0x3F80 : (v[i] < 0.f ? 0xBF80 : 0);
  ((uint4*)o)[t] = pk.u;
}

// ---------------- fused layernorm + activation_quant -> int8 q + row scale ----------------
__global__ void norm_quant_i8_kernel(const float* __restrict__ x,
                                     char* __restrict__ q, float* __restrict__ inv) {
  const int row  = blockIdx.x;
  const int tid  = threadIdx.x;
  const int lane = tid & 63, wave = tid >> 6;
  const float4* xr = (const float4*)(x + (size_t)row * DDIM);
  float4 a = xr[tid * 2], b = xr[tid * 2 + 1];
  float v[8] = {a.x, a.y, a.z, a.w, b.x, b.y, b.z, b.w};
  float s1 = 0.f, s2 = 0.f;
#pragma unroll
  for (int i = 0; i < 8; i++) { s1 += v[i]; s2 += v[i] * v[i]; }
#pragma unroll
  for (int o = 1; o < 64; o <<= 1) { s1 += __shfl_xor(s1, o); s2 += __shfl_xor(s2, o); }
  __shared__ float ssum[4], ssq[4], smax[4];
  if (lane == 0) { ssum[wave] = s1; ssq[wave] = s2; }
  __syncthreads();
  s1 = ssum[0] + ssum[1] + ssum[2] + ssum[3];
  s2 = ssq[0] + ssq[1] + ssq[2] + ssq[3];
  const float mean = s1 * (1.f / DDIM);
  const float var  = s2 * (1.f / DDIM) - mean * mean;
  const float rstd = rsqrtf(var + 1e-8f);
  float mx = 0.f;
#pragma unroll
  for (int i = 0; i < 8; i++) { v[i] = (v[i] - mean) * rstd; mx = fmaxf(mx, fabsf(v[i])); }
#pragma unroll
  for (int o = 1; o < 64; o <<= 1) mx = fmaxf(mx, __shfl_xor(mx, o));
  if (lane == 0) smax[wave] = mx;
  __syncthreads();
  mx = fmaxf(fmaxf(smax[0], smax[1]), fmaxf(smax[2], smax[3]));
  const float s = 127.f / mx;
  if (tid == 0) inv[row] = mx * (1.f / 127.f);
  union { char s8[8]; uint2 u; } pk;
#pragma unroll
  for (int i = 0; i < 8; i++) {
    float qq = rintf(v[i] * s);               // round half-to-even like jnp.round
    qq = fminf(fmaxf(qq, -128.f), 127.f);
    pk.s8[i] = (char)(int)qq;
  }
  ((uint2*)(q + (size_t)row * DDIM))[tid] = pk.u;
}

// ---------------- fused GEMM1+2 (int8): p = silu(g)*u, exact integer dot ----------------
// r0/r5-proven anchor: 128x128 tile, BK=128 bytes, XOR-swizzled LDS, XCD-rect block
// swizzle, 48KB LDS, launch_bounds(256,2). 266-277us @ 45-49% MfmaUtil.
// NOTE (r6 lesson): acc footprint = 128 AGPR + ~108 VGPR ~ 236/512 unified regs
// -> hard cap 2 blocks/CU. launch_bounds(256,3) forces spill (WRITE_SIZE 131->501MB,
// 606us). Do NOT raise the min-waves arg.
__global__ __launch_bounds__(256, 2) void gemm_glu_i8_kernel(
    const char* __restrict__ A,   // q [MROWS, DDIM] int8
    const char* __restrict__ Bg,  // sign(W_g) [HDIM, DDIM] int8
    const char* __restrict__ Bu,  // sign(W_u) [HDIM, DDIM] int8
    const float* __restrict__ inv,
    u16* __restrict__ P)          // [MROWS, HDIM] bf16
{
  constexpr int K = DDIM;         // bytes per row (int8)
  // XCD-aware swizzle: XCD x owns n-tiles [8x, 8x+8); consecutive slots share m-stripe.
  const int l   = blockIdx.x + gridDim.x * blockIdx.y;  // 0..4095
  const int xcd = l & 7;
  const int s_  = l >> 3;                               // 0..511
  const int n0 = (xcd * 8 + (s_ & 7)) * 128;
  const int m0 = (s_ >> 3) * 128;
  const int tid  = threadIdx.x;
  const int lane = tid & 63, wave = tid >> 6;
  const int wm = wave >> 1, wn = wave & 1;
  const int quad = lane >> 4, l16 = lane & 15;

  __shared__ __align__(16) char lds[49152];
  char* lA  = lds;
  char* lBg = lds + 16384;
  char* lBu = lds + 32768;

  i32x4 accg[4][4], accu[4][4];
  const i32x4 zero = {0, 0, 0, 0};
#pragma unroll
  for (int i = 0; i < 4; i++)
#pragma unroll
    for (int j = 0; j < 4; j++) { accg[i][j] = zero; accu[i][j] = zero; }

  const int arow = wm * 64 + l16;
  const int brow = wn * 64 + l16;
  const int aswz = (arow & 7) << 4;
  const int bswz = (brow & 7) << 4;

  for (int k0 = 0; k0 < K; k0 += 128) {
    __syncthreads();
#pragma unroll
    for (int is = 0; is < 4; ++is) {
      const int o   = is * 4096 + tid * 16;
      const int r   = o >> 7;                      // tile row 0..127
      const int cbs = (o & 127) ^ ((r & 7) << 4);  // swizzled byte-in-row
      async_load16(A  + (size_t)(m0 + r) * K + k0 + cbs, lA  + is * 4096 + wave * 1024);
      async_load16(Bg + (size_t)(n0 + r) * K + k0 + cbs, lBg + is * 4096 + wave * 1024);
      async_load16(Bu + (size_t)(n0 + r) * K + k0 + cbs, lBu + is * 4096 + wave * 1024);
    }
    __syncthreads();
#pragma unroll
    for (int ks = 0; ks < 2; ++ks) {
      const int koff = ks * 64 + quad * 16;
      i32x4 a[4], bg[4], bu[4];
#pragma unroll
      for (int i = 0; i < 4; i++)
        a[i] = *(const i32x4*)(lA + (arow + i * 16) * 128 + (koff ^ aswz));
#pragma unroll
      for (int j = 0; j < 4; j++) {
        bg[j] = *(const i32x4*)(lBg + (brow + j * 16) * 128 + (koff ^ bswz));
        bu[j] = *(const i32x4*)(lBu + (brow + j * 16) * 128 + (koff ^ bswz));
      }
#pragma unroll
      for (int i = 0; i < 4; i++)
#pragma unroll
        for (int j = 0; j < 4; j++) {
          accg[i][j] = __builtin_amdgcn_mfma_i32_16x16x64_i8(a[i], bg[j], accg[i][j], 0, 0, 0);
          accu[i][j] = __builtin_amdgcn_mfma_i32_16x16x64_i8(a[i], bu[j], accu[i][j], 0, 0, 0);
        }
    }
  }

  // epilogue: g,u exact ints scaled by row scale; p = silu(g)*u -> bf16
  const int rbase = m0 + wm * 64 + quad * 4;
  const int cbase = n0 + wn * 64 + l16;
#pragma unroll
  for (int i = 0; i < 4; i++) {
    float iv[4];
#pragma unroll
    for (int r = 0; r < 4; r++) iv[r] = inv[rbase + i * 16 + r];
#pragma unroll
    for (int j = 0; j < 4; j++)
#pragma unroll
      for (int r = 0; r < 4; r++) {
        float g = (float)accg[i][j][r] * iv[r];
        float u = (float)accu[i][j][r] * iv[r];
        float pv = (g / (1.f + __expf(-g))) * u;
        P[(size_t)(rbase + i * 16 + r) * HDIM + (cbase + j * 16)] = f2bf(pv);
      }
  }
}

// ---------------- GEMM3: out = p @ sign(W_d)^T, bf16 in / fp32 out ----------------
// m201 geometry: BM=BN=256, BK=128B (64 bf16), 8 waves (2Mx4N), 128x64/wave.
// Counted vmcnt (see tile-boundary comment). Rect-XCD swizzle: each XCD owns a
// 4n x 8m rectangle -> per-XCD L2 fill 48MB (4 B-panels + 8 P-stripes) vs 132MB
// for the 1n x 32m column mapping. Predicted FETCH_SIZE 540 -> ~350MB.
__global__ __launch_bounds__(512, 2) void gemm_out_kernel(
    const u16* __restrict__ A,  // p [MROWS, HDIM]
    const u16* __restrict__ B,  // sign(W_d) [DDIM, HDIM]
    float* __restrict__ C)      // [MROWS, DDIM]
{
  constexpr size_t KB = (size_t)HDIM * 2;  // 16384 bytes per row
  constexpr int NT = (int)(KB / 128);      // 128 K-tiles
  const int l   = blockIdx.x + gridDim.x * blockIdx.y;  // grid (8,32) -> 0..255
  const int xcd = l & 7;
  const int s_  = l >> 3;                               // 0..31
  const int n0 = ((xcd & 1) * 4 + (s_ & 3)) * 256;      // 8 n-positions
  const int m0 = ((xcd >> 1) * 8 + (s_ >> 2)) * 256;    // 32 m-positions
  const int tid  = threadIdx.x;
  const int lane = tid & 63, wave = tid >> 6;
  const int wm = wave >> 2, wn = wave & 3;
  const int quad = lane >> 4, l16 = lane & 15;

  __shared__ __align__(16) char lds[131072];

  f32x4 acc[8][4];
  const f32x4 zero = {0.f, 0.f, 0.f, 0.f};
#pragma unroll
  for (int i = 0; i < 8; i++)
#pragma unroll
    for (int j = 0; j < 4; j++) acc[i][j] = zero;

  const int arow = wm * 128 + l16;
  const int brow = wn * 64 + l16;
  const int swz  = (l16 & 7) << 4;

  const int rr  = tid >> 3;
  const int cbs = ((tid & 7) << 4) ^ ((rr & 7) << 4);
  const char* aSrc = (const char*)A + (size_t)(m0 + rr) * KB + cbs;
  const char* bSrc = (const char*)B + (size_t)(n0 + rr) * KB + cbs;

#define STG2_A(is) async_load16(aSrc + (size_t)(is) * 64 * KB + k0n, bufN + (is) * 8192 + wave * 1024)
#define STG2_B(is) async_load16(bSrc + (size_t)(is) * 64 * KB + k0n, bufN + 32768 + (is) * 8192 + wave * 1024)
#define STG2_TILE() do { STG2_A(0); STG2_A(1); STG2_A(2); STG2_A(3); \
                         STG2_B(0); STG2_B(1); STG2_B(2); STG2_B(3); } while (0)

  {
    char* bufN = lds;           const int k0n = 0;
    STG2_TILE();
  }
  {
    char* bufN = lds + 65536;   const int k0n = 128;
    STG2_TILE();
  }
  asm volatile("s_waitcnt vmcnt(8)" ::: "memory");
  __builtin_amdgcn_s_barrier();

  for (int t = 0; t < NT; ++t) {
    const char* bufC = lds + (size_t)(t & 1) * 65536;
    bf16x8 b[4];
#pragma unroll
    for (int ks = 0; ks < 2; ++ks) {
#pragma unroll
      for (int ih = 0; ih < 2; ++ih) {
        const int koff = (ks * 64 + quad * 16) ^ swz;
        if (ih == 0) {  // B frags once per ks, reused across ih phases
#pragma unroll
          for (int j = 0; j < 4; ++j)
            b[j] = *(const bf16x8*)(bufC + 32768 + (size_t)(brow + j * 16) * 128 + koff);
        }
        bf16x8 a[4];
#pragma unroll
        for (int ii = 0; ii < 4; ++ii)
          a[ii] = *(const bf16x8*)(bufC + (size_t)(arow + (ih * 4 + ii) * 16) * 128 + koff);
        __builtin_amdgcn_s_barrier();     // phase barrier
        __builtin_amdgcn_s_setprio(1);
#pragma unroll
        for (int ii = 0; ii < 4; ++ii) {
          const int i = ih * 4 + ii;
#pragma unroll
          for (int j = 0; j < 4; ++j)
            acc[i][j] = __builtin_amdgcn_mfma_f32_16x16x32_bf16(a[ii], b[j], acc[i][j], 0, 0, 0);
        }
        __builtin_amdgcn_s_setprio(0);
      }
    }
    __builtin_amdgcn_s_barrier();         // B1: all reads of bufC done
    if (t + 2 < NT) {
      char* bufN = lds + (size_t)(t & 1) * 65536;
      const int k0n = (t + 2) * 128;
      STG2_TILE();
      asm volatile("s_waitcnt vmcnt(8)" ::: "memory");
    } else {
      asm volatile("s_waitcnt vmcnt(0)" ::: "memory");
    }
    __builtin_amdgcn_s_barrier();
  }
#undef STG2_A
#undef STG2_B
#undef STG2_TILE

  const int rbase = m0 + wm * 128 + quad * 4;
  const int cbase = n0 + wn * 64 + l16;
#pragma unroll
  for (int i = 0; i < 8; i++)
#pragma unroll
    for (int j = 0; j < 4; j++)
#pragma unroll
      for (int r = 0; r < 4; r++)
        C[(size_t)(rbase + i * 16 + r) * DDIM + (cbase + j * 16)] = acc[i][j][r];
}

extern "C" void kernel_launch(void* const* d_in, const int* in_sizes, int n_in,
                              void* d_out, int out_size, void* d_ws, size_t ws_size,
                              hipStream_t stream) {
  const float* x  = (const float*)d_in[0];
  const float* Wg = (const float*)d_in[1];
  const float* Wu = (const float*)d_in[2];
  const float* Wd = (const float*)d_in[3];

  char* ws = (char*)d_ws;
  // layout: q(16MB) | inv(32KB @16MB) | sWg_i8(16MB @20MB) | sWu_i8(16MB @36MB)
  //         | sWd_bf16(32MB @52MB) | p(128MB @84MB)  -> 212MB total
  char*  q    = ws;
  float* inv  = (float*)(ws + 16777216ull);
  char*  sWg  = ws + 20971520ull;
  char*  sWu  = ws + 37748736ull;
  u16*   sWd  = (u16*)(ws + 54525952ull);
  u16*   p    = (u16*)(ws + 88080384ull);
  float* out  = (float*)d_out;

  dim3 gs(8192, 2);
  sign_i8x2_kernel<<<gs, 256, 0, stream>>>(Wg, Wu, sWg, sWu);
  sign_bf16_kernel<<<8192, 256, 0, stream>>>(Wd, sWd);

  norm_quant_i8_kernel<<<MROWS, 256, 0, stream>>>(x, q, inv);

  dim3 g1(HDIM / 128, MROWS / 128);   // 64 x 64 = 4096 blocks
  gemm_glu_i8_kernel<<<g1, 256, 0, stream>>>(q, sWg, sWu, inv, p);

  dim3 g2(DDIM / 256, MROWS / 256);   // 8 x 32 = 256 blocks
  gemm_out_kernel<<<g2, 512, 0, stream>>>(p, sWd, out);
}